// Round 15
// baseline (181.852 us; speedup 1.0000x reference)
//
#include <hip/hip_runtime.h>
#include <math.h>

#define NIMG 96
#define NSLOT 1024
#define RES_INV (1.0f / 262144.0f)   // 1 / (512*512)

__device__ __forceinline__ float wrap1(float v) {
  float t = v + 1.0f;
  return t - 2.0f * truncf(t * 0.5f) - 1.0f;
}
__device__ __forceinline__ int bin_fast(float v) {
  int b = (int)fmaf(v, 128.0f, 128.0f);
  return (b > 255) ? 255 : b;
}

// ---------------- lvl0 x-kernel with per-thread BYTE histograms -------------
// No atomics in the hot path: each thread owns a private 512-bin u8 histogram
// (img bins 0..255 at +0, xo-delta bins at +256), stride 516 B (odd word
// stride 129 -> bank-decorrelated). Update = plain u8 RMW (2 DS ops at full
// throughput) instead of atomicAdd (~1 lane/cyc RMW arbitration).
// Block = 64 rows (wave = 16 rows, 4-deep row prefetch). Flush: packed u16
// byte-sums, 128 u32 reads/thread, then few global atomics.
__global__ void __launch_bounds__(256, 1) kx4_bh(
    const float* __restrict__ src, float* __restrict__ xe_out,
    const float* __restrict__ kpx, const float* __restrict__ kux,
    const float* __restrict__ kcx, const float* __restrict__ krx,
    double* __restrict__ partial,
    unsigned* __restrict__ hist_img, unsigned* __restrict__ hist_delta)
{
  constexpr int W2 = 256, H = 512;
  constexpr int STRB = 516;            // byte stride per copy (129 words, odd)
  __shared__ unsigned char bh[256 * STRB];

  const int t = threadIdx.x, w = t >> 6, lane = t & 63;
  const int img = blockIdx.y;
  const int r0 = blockIdx.x * 64 + w * 16;

  unsigned* bw = (unsigned*)bh;
  for (int i = t; i < 256 * (STRB / 4); i += 256) bw[i] = 0;
  __syncthreads();

  const float px0 = kpx[0], px1 = kpx[1], px2 = kpx[2];
  const float ux0 = kux[0], ux1 = kux[1], ux2 = kux[2];
  const float cx0 = kcx[0], cx1 = kcx[1], cx2 = kcx[2];
  const float rx0 = krx[0], rx1 = krx[1], rx2 = krx[2];

  const float* ip = src + (size_t)img * H * (2 * W2);
  unsigned char* myh = &bh[t * STRB];
  float sqi = 0.f, sqd = 0.f;

  auto stepm = [&](float (&d)[4], float (&s)[4], float k0, float k1, float k2) {
    float L = __shfl_up(s[3], 1); if (lane == 0) L = 0.f;
    float R = __shfl_down(s[0], 1); if (lane == 63) R = 0.f;
    float prev = L;
#pragma unroll
    for (int j = 0; j < 4; j++) {
      float nxt = (j == 3) ? R : s[j + 1 < 4 ? j + 1 : 0];
      d[j] = fmaf(k0, prev, fmaf(k1, s[j], fmaf(k2, nxt, d[j])));
      prev = s[j];
    }
  };

  // 4-deep row prefetch pipeline
  float4 A[4], B[4];
#pragma unroll
  for (int j = 0; j < 4; ++j) {
    const float* rp = ip + (size_t)(r0 + j) * (2 * W2) + lane * 8;
    A[j] = *(const float4*)rp;
    B[j] = *(const float4*)(rp + 4);
  }

  for (int r = 0; r < 16; ++r) {
    const int cur = r & 3;
    float e[4], o[4];
    e[0] = A[cur].x; o[0] = A[cur].y; e[1] = A[cur].z; o[1] = A[cur].w;
    e[2] = B[cur].x; o[2] = B[cur].y; e[3] = B[cur].z; o[3] = B[cur].w;
    if (r + 4 < 16) {
      const float* rp = ip + (size_t)(r0 + r + 4) * (2 * W2) + lane * 8;
      A[cur] = *(const float4*)rp;
      B[cur] = *(const float4*)(rp + 4);
    }
    // img stats (byte-hist, no atomic)
#pragma unroll
    for (int j = 0; j < 4; j++) {
      sqi += e[j] * e[j] + o[j] * o[j];
      myh[bin_fast(e[j])]++;
      myh[bin_fast(o[j])]++;
    }
    stepm(o, e, -px0, -px1, -px2);
    stepm(e, o,  ux0,  ux1,  ux2);
    stepm(o, e, -cx0, -cx1, -cx2);
    stepm(e, o,  rx0,  rx1,  rx2);
    float* orow = xe_out + ((size_t)img * H + r0 + r) * W2;
    *(float4*)(orow + lane * 4) = make_float4(e[0], e[1], e[2], e[3]);
#pragma unroll
    for (int j = 0; j < 4; j++) {
      float d = wrap1(o[j]);
      sqd += d * d;
      myh[256 + bin_fast(d)]++;
    }
  }

  for (int off = 32; off; off >>= 1) {
    sqd += __shfl_down(sqd, off);
    sqi += __shfl_down(sqi, off);
  }
  if (lane == 0) {
    const int bid = blockIdx.x + blockIdx.y * gridDim.x;
    const int slot = (bid * 4 + w) & (NSLOT - 1);
    atomicAdd(&partial[NSLOT + slot], (double)sqd);
    atomicAdd(&partial[slot], (double)sqi);
  }
  __syncthreads();

  // flush: word g of each copy holds 4 adjacent bins as bytes
  {
    const int h = t >> 7;          // which 128 copies
    const int g = t & 127;         // word index 0..127 (128 data words/copy)
    unsigned s0 = 0, s1 = 0;
    for (int c = h * 128; c < h * 128 + 128; ++c) {
      unsigned wv = bw[c * (STRB / 4) + g];
      s0 += wv & 0x00FF00FFu;
      s1 += (wv >> 8) & 0x00FF00FFu;
    }
    const unsigned b0 = s0 & 0xFFFFu, b2 = s0 >> 16;
    const unsigned b1 = s1 & 0xFFFFu, b3 = s1 >> 16;
    unsigned* dst = (g < 64) ? &hist_img[img * 256 + 4 * g]
                             : &hist_delta[img * 256 + 4 * (g - 64)];
    if (b0) atomicAdd(dst + 0, b0);
    if (b1) atomicAdd(dst + 1, b1);
    if (b2) atomicAdd(dst + 2, b2);
    if (b3) atomicAdd(dst + 3, b3);
  }
}

// ---------------- x-lift kernel (atomic hists) for lvl1/lvl2 ----------------
template<int P, int DO_IMG>
__global__ void __launch_bounds__(256) kx(
    const float* __restrict__ src, float* __restrict__ xe_out,
    const float* __restrict__ kpx, const float* __restrict__ kux,
    const float* __restrict__ kcx, const float* __restrict__ krx,
    double* __restrict__ partial,
    unsigned* __restrict__ hist_img, unsigned* __restrict__ hist_delta)
{
  constexpr int W2 = 64 * P;
  constexpr int H  = 128 * P;
  __shared__ unsigned shd[2][257];

  const int t = threadIdx.x, w = t >> 6, lane = t & 63;
  const int hsel = w >> 1;
  const int img = blockIdx.y;
  const int r0 = blockIdx.x * 16 + w * 4;

  for (int i = t; i < 2 * 257; i += 256) ((unsigned*)shd)[i] = 0;
  __syncthreads();

  const float px0 = kpx[0], px1 = kpx[1], px2 = kpx[2];
  const float ux0 = kux[0], ux1 = kux[1], ux2 = kux[2];
  const float cx0 = kcx[0], cx1 = kcx[1], cx2 = kcx[2];
  const float rx0 = krx[0], rx1 = krx[1], rx2 = krx[2];

  const float* ip = src + (size_t)img * H * (2 * W2);
  float sqd = 0.f;

  auto stepm = [&](float (&d)[P], float (&s)[P], float k0, float k1, float k2) {
    float L = __shfl_up(s[P - 1], 1); if (lane == 0) L = 0.f;
    float R = __shfl_down(s[0], 1);   if (lane == 63) R = 0.f;
    float prev = L;
#pragma unroll
    for (int j = 0; j < P; j++) {
      float nxt = (j == P - 1) ? R : s[(j + 1) < P ? (j + 1) : 0];
      d[j] = fmaf(k0, prev, fmaf(k1, s[j], fmaf(k2, nxt, d[j])));
      prev = s[j];
    }
  };

  float4 A[4], B[4];
#pragma unroll
  for (int j = 0; j < 4; ++j) {
    const float* rp = ip + (size_t)(r0 + j) * (2 * W2) + lane * (2 * P);
    if (P == 1) { float2 v = *(const float2*)rp; A[j].x = v.x; A[j].y = v.y; }
    else {
      A[j] = *(const float4*)rp;
      if (P == 4) B[j] = *(const float4*)(rp + 4);
    }
  }

#pragma unroll
  for (int j = 0; j < 4; ++j) {
    float e[P], o[P];
    e[0] = A[j].x; o[0] = A[j].y;
    if (P >= 2) { e[P > 1 ? 1 : 0] = A[j].z; o[P > 1 ? 1 : 0] = A[j].w; }
    if (P == 4) {
      e[P > 2 ? 2 : 0] = B[j].x; o[P > 2 ? 2 : 0] = B[j].y;
      e[P > 3 ? 3 : 0] = B[j].z; o[P > 3 ? 3 : 0] = B[j].w;
    }
    stepm(o, e, -px0, -px1, -px2);
    stepm(e, o,  ux0,  ux1,  ux2);
    stepm(o, e, -cx0, -cx1, -cx2);
    stepm(e, o,  rx0,  rx1,  rx2);
    float* orow = xe_out + ((size_t)img * H + r0 + j) * W2;
    if (P == 4) {
      *(float4*)(orow + lane * 4) =
          make_float4(e[0], e[P > 1 ? 1 : 0], e[P > 2 ? 2 : 0], e[P > 3 ? 3 : 0]);
    } else if (P == 2) {
      *(float2*)(orow + lane * 2) = make_float2(e[0], e[P > 1 ? 1 : 0]);
    } else {
      orow[lane] = e[0];
    }
#pragma unroll
    for (int jj = 0; jj < P; jj++) {
      float d = wrap1(o[jj]);
      sqd += d * d;
      atomicAdd(&shd[hsel][bin_fast(d)], 1u);
    }
  }

  for (int off = 32; off; off >>= 1) sqd += __shfl_down(sqd, off);
  if (lane == 0) {
    const int bid = blockIdx.x + blockIdx.y * gridDim.x;
    const int slot = (bid * 4 + w) & (NSLOT - 1);
    atomicAdd(&partial[NSLOT + slot], (double)sqd);
  }
  __syncthreads();
  unsigned hd = shd[0][t] + shd[1][t];
  if (hd) atomicAdd(&hist_delta[img * 256 + t], hd);
}

// ---------------- y-lift kernel: thread = column x 16-row segment -----------
template<int P, int USE_UY>
__global__ void __launch_bounds__(256) ky(
    const float* __restrict__ xe, float* __restrict__ ye_out,
    const float* __restrict__ kpy, const float* __restrict__ kuy,
    const float* __restrict__ kcy, const float* __restrict__ kry,
    double* __restrict__ partial, unsigned* __restrict__ hist_delta)
{
  constexpr int W2 = 64 * P;
  constexpr int H2 = W2;
  constexpr int NSP = 256 / W2;
  constexpr int SEG = 16, WIN = 24;
  __shared__ unsigned shd[2][257];

  const int t = threadIdx.x;
  const int img = blockIdx.y;
  const int col = t % W2;
  const int half = t / W2;
  const int r0 = (blockIdx.x * NSP + half) * SEG;
  const int hsel = (t >> 7) & 1;

  for (int i = t; i < 2 * 257; i += 256) ((unsigned*)shd)[i] = 0;
  __syncthreads();

  const float py0 = kpy[0], py1 = kpy[1], py2 = kpy[2];
  const float uy0 = kuy[0], uy1 = kuy[1], uy2 = kuy[2];
  const float cy0 = kcy[0], cy1 = kcy[1], cy2 = kcy[2];
  const float ry0 = kry[0], ry1 = kry[1], ry2 = kry[2];

  const float* xin = xe + (size_t)img * (2 * H2) * W2 + col;
  float ee[WIN], oo[WIN];
#pragma unroll
  for (int q = 0; q < WIN; ++q) {
    const int g = r0 + q - 4;
    const int gc = (g < 0) ? 0 : ((g >= H2) ? (H2 - 1) : g);
    float v0 = xin[(size_t)(2 * gc) * W2];
    float v1 = xin[(size_t)(2 * gc) * W2 + W2];
    const bool ok = (unsigned)g < (unsigned)H2;
    ee[q] = ok ? v0 : 0.f;
    oo[q] = ok ? v1 : 0.f;
  }
#pragma unroll
  for (int q = 0; q < WIN; ++q) {
    float U = (q > 0) ? ee[q - 1] : 0.f;
    float D = (q < WIN - 1) ? ee[q + 1] : 0.f;
    oo[q] = fmaf(-py0, U, fmaf(-py1, ee[q], fmaf(-py2, D, oo[q])));
  }
  if (USE_UY) {
#pragma unroll
    for (int q = 0; q < WIN; ++q) {
      float U = (q > 0) ? oo[q - 1] : 0.f;
      float D = (q < WIN - 1) ? oo[q + 1] : 0.f;
      ee[q] = fmaf(uy0, U, fmaf(uy1, oo[q], fmaf(uy2, D, ee[q])));
    }
  }
#pragma unroll
  for (int q = 0; q < WIN; ++q) {
    float U = (q > 0) ? ee[q - 1] : 0.f;
    float D = (q < WIN - 1) ? ee[q + 1] : 0.f;
    oo[q] = fmaf(-cy0, U, fmaf(-cy1, ee[q], fmaf(-cy2, D, oo[q])));
  }
#pragma unroll
  for (int q = 0; q < WIN; ++q) {
    float U = (q > 0) ? oo[q - 1] : 0.f;
    float D = (q < WIN - 1) ? oo[q + 1] : 0.f;
    ee[q] = fmaf(ry0, U, fmaf(ry1, oo[q], fmaf(ry2, D, ee[q])));
  }

  float sqd = 0.f;
  float* outp = ye_out + (size_t)img * H2 * W2 + col;
#pragma unroll
  for (int q = 4; q < 4 + SEG; ++q) {
    const int g = r0 + q - 4;
    float d = wrap1(oo[q]);
    sqd += d * d;
    atomicAdd(&shd[hsel][bin_fast(d)], 1u);
    outp[(size_t)g * W2] = ee[q];
  }

  for (int off = 32; off; off >>= 1) sqd += __shfl_down(sqd, off);
  if ((t & 63) == 0) {
    const int bid = blockIdx.x + blockIdx.y * gridDim.x;
    atomicAdd(&partial[NSLOT + ((bid * 4 + (t >> 6)) & (NSLOT - 1))], (double)sqd);
  }
  __syncthreads();
  unsigned hd = shd[0][t] + shd[1][t];
  if (hd) atomicAdd(&hist_delta[img * 256 + t], hd);
}

// ---------------- Tail: levels 3-4 on 64x64 in LDS, 1 block = 1 image -------
__global__ void __launch_bounds__(256) klift_tail64(
    const float* __restrict__ src,
    const float* __restrict__ kpx, const float* __restrict__ kux,
    const float* __restrict__ kcx, const float* __restrict__ krx,
    const float* __restrict__ kpy, const float* __restrict__ kcy,
    const float* __restrict__ kry,
    double* __restrict__ partial, unsigned* __restrict__ hist_delta)
{
  __shared__ float tile[64][65];
  __shared__ unsigned shd[2][257];
  const int t = threadIdx.x;
  const int img = blockIdx.x;
  const int cd = t & 1;
  for (int i = t; i < 2 * 257; i += 256) ((unsigned*)shd)[i] = 0;

  const float* sp = src + (size_t)img * 64 * 64;
  for (int idx = t; idx < 64 * 16; idx += 256) {
    const int r = idx >> 4, c4 = (idx & 15) << 2;
    float4 v = *(const float4*)(sp + r * 64 + c4);
    tile[r][c4] = v.x; tile[r][c4 + 1] = v.y;
    tile[r][c4 + 2] = v.z; tile[r][c4 + 3] = v.w;
  }
  const float px0 = kpx[0], px1 = kpx[1], px2 = kpx[2];
  const float ux0 = kux[0], ux1 = kux[1], ux2 = kux[2];
  const float cx0 = kcx[0], cx1 = kcx[1], cx2 = kcx[2];
  const float rx0 = krx[0], rx1 = krx[1], rx2 = krx[2];
  const float pc0 = kpy[0] + kcy[0], pc1 = kpy[1] + kcy[1], pc2 = kpy[2] + kcy[2];
  const float ry0 = kry[0], ry1 = kry[1], ry2 = kry[2];
  float sqd = 0.f;
  __syncthreads();

  for (int l = 0; l < 2; ++l) {
    const int s = 1 << l, n = 64 >> l, half = n >> 1;
    const int totx = n * half;

    for (int idx = t; idx < totx; idx += 256) {
      const int r = (idx / half) * s, c = idx % half;
      float L = (c > 0) ? tile[r][(2 * c - 2) * s] : 0.f;
      float M = tile[r][2 * c * s];
      float R = (c < half - 1) ? tile[r][(2 * c + 2) * s] : 0.f;
      tile[r][(2 * c + 1) * s] -= px0 * L + px1 * M + px2 * R;
    }
    __syncthreads();
    for (int idx = t; idx < totx; idx += 256) {
      const int r = (idx / half) * s, c = idx % half;
      float L = (c > 0) ? tile[r][(2 * c - 1) * s] : 0.f;
      float M = tile[r][(2 * c + 1) * s];
      float R = (c < half - 1) ? tile[r][(2 * c + 3) * s] : 0.f;
      tile[r][2 * c * s] += ux0 * L + ux1 * M + ux2 * R;
    }
    __syncthreads();
    for (int idx = t; idx < totx; idx += 256) {
      const int r = (idx / half) * s, c = idx % half;
      float L = (c > 0) ? tile[r][(2 * c - 2) * s] : 0.f;
      float M = tile[r][2 * c * s];
      float R = (c < half - 1) ? tile[r][(2 * c + 2) * s] : 0.f;
      tile[r][(2 * c + 1) * s] -= cx0 * L + cx1 * M + cx2 * R;
    }
    __syncthreads();
    for (int idx = t; idx < totx; idx += 256) {
      const int r = (idx / half) * s, c = idx % half;
      float L = (c > 0) ? tile[r][(2 * c - 1) * s] : 0.f;
      float M = tile[r][(2 * c + 1) * s];
      float R = (c < half - 1) ? tile[r][(2 * c + 3) * s] : 0.f;
      tile[r][2 * c * s] += rx0 * L + rx1 * M + rx2 * R;
    }
    __syncthreads();
    for (int idx = t; idx < totx; idx += 256) {
      const int r = (idx / half) * s, c = idx % half;
      float d = wrap1(tile[r][(2 * c + 1) * s]);
      sqd += d * d;
      atomicAdd(&shd[cd][bin_fast(d)], 1u);
    }
    const int toty = half * half;
    for (int idx = t; idx < toty; idx += 256) {
      const int r = idx / half, j = idx % half, col = j * 2 * s;
      float U = (r > 0) ? tile[(2 * r - 2) * s][col] : 0.f;
      float M = tile[(2 * r) * s][col];
      float D = (r < half - 1) ? tile[(2 * r + 2) * s][col] : 0.f;
      tile[(2 * r + 1) * s][col] -= pc0 * U + pc1 * M + pc2 * D;
    }
    __syncthreads();
    for (int idx = t; idx < toty; idx += 256) {
      const int r = idx / half, j = idx % half, col = j * 2 * s;
      float U = (r > 0) ? tile[(2 * r - 1) * s][col] : 0.f;
      float M = tile[(2 * r + 1) * s][col];
      float D = (r < half - 1) ? tile[(2 * r + 3) * s][col] : 0.f;
      tile[(2 * r) * s][col] += ry0 * U + ry1 * M + ry2 * D;
    }
    __syncthreads();
    for (int idx = t; idx < toty; idx += 256) {
      const int r = idx / half, j = idx % half, col = j * 2 * s;
      float d = wrap1(tile[(2 * r + 1) * s][col]);
      sqd += d * d;
      atomicAdd(&shd[cd][bin_fast(d)], 1u);
      if (l == 1) {
        float d2 = wrap1(tile[(2 * r) * s][col]);
        sqd += d2 * d2;
        atomicAdd(&shd[cd][bin_fast(d2)], 1u);
      }
    }
    __syncthreads();
  }

  for (int off = 32; off; off >>= 1) sqd += __shfl_down(sqd, off);
  __shared__ float swv[4];
  if ((t & 63) == 0) swv[t >> 6] = sqd;
  __syncthreads();
  if (t == 0) {
    double tot = (double)swv[0] + swv[1] + swv[2] + swv[3];
    atomicAdd(&partial[NSLOT + (img & (NSLOT - 1))], tot);
  }
  unsigned hd = shd[0][t] + shd[1][t];
  if (hd) atomicAdd(&hist_delta[img * 256 + t], hd);
}

// ---------------- Final reduction: entropies + losses -----------------------
__global__ void __launch_bounds__(256) kfinal(
    const double* __restrict__ partial,
    const unsigned* __restrict__ hist_img,
    const unsigned* __restrict__ hist_delta,
    float* __restrict__ out)
{
  __shared__ double sI[256], sD[256], sPi[256], sPd[256];
  const int t = threadIdx.x;
  double entI = 0.0, entD = 0.0;
  for (int img = 0; img < NIMG; ++img) {
    unsigned ci = hist_img[img * 256 + t];
    if (ci) { float p = (float)ci * RES_INV; entI += (double)(-p * log2f(p)); }
    unsigned cd = hist_delta[img * 256 + t];
    if (cd) { float p = (float)cd * RES_INV; entD += (double)(-p * log2f(p)); }
  }
  double pi = 0.0, pd = 0.0;
  for (int s = t; s < NSLOT; s += 256) {
    pi += partial[s];
    pd += partial[NSLOT + s];
  }
  sI[t] = entI; sD[t] = entD; sPi[t] = pi; sPd[t] = pd;
  __syncthreads();
  for (int s = 128; s; s >>= 1) {
    if (t < s) {
      sI[t] += sI[t + s]; sD[t] += sD[t + s];
      sPi[t] += sPi[t + s]; sPd[t] += sPd[t + s];
    }
    __syncthreads();
  }
  if (t == 0) {
    const double tot = (double)NIMG * 262144.0;
    out[0] = (float)(255.0 * sqrt(sPd[0] / tot));  // loss1 (deltas)
    out[1] = (float)(255.0 * sqrt(sPi[0] / tot));  // loss0 (img)
    out[2] = (float)(sI[0] / (8.0 * NIMG));        // invCR0
    out[3] = (float)(sD[0] / (8.0 * NIMG));        // invCR1
  }
}

extern "C" void kernel_launch(void* const* d_in, const int* in_sizes, int n_in,
                              void* d_out, int out_size, void* d_ws, size_t ws_size,
                              hipStream_t stream)
{
  const float* x  = (const float*)d_in[0];
  const float* px = (const float*)d_in[1];
  const float* ux = (const float*)d_in[2];
  const float* cx = (const float*)d_in[3];
  const float* rx = (const float*)d_in[4];
  const float* py = (const float*)d_in[5];
  const float* uy = (const float*)d_in[6];
  const float* cy = (const float*)d_in[7];
  const float* ry = (const float*)d_in[8];
  float* out = (float*)d_out;

  char* ws = (char*)d_ws;
  double*   partial    = (double*)ws;
  unsigned* hist_img   = (unsigned*)(ws + 2 * NSLOT * 8);
  unsigned* hist_delta = (unsigned*)(ws + 2 * NSLOT * 8 + NIMG * 256 * 4);
  float* bxe  = (float*)(ws + ((size_t)1 << 20));    // xe scratch (<=48MB, reused)
  float* bye0 = (float*)(ws + ((size_t)50 << 20));   // ye0: 25.2MB
  float* bye1 = (float*)(ws + ((size_t)76 << 20));   // ye1: 6.3MB
  float* bye2 = (float*)(ws + ((size_t)83 << 20));   // ye2: 1.6MB

  hipMemsetAsync(ws, 0, 2 * NSLOT * 8 + 2 * NIMG * 256 * 4, stream);

  // level 0: x (byte-hist, no atomics) then y -> ye0 (256x256)
  kx4_bh<<<dim3(8, NIMG), 256, 0, stream>>>(
      x, bxe, px, ux, cx, rx, partial, hist_img, hist_delta);
  ky<4, 1><<<dim3(16, NIMG), 256, 0, stream>>>(
      bxe, bye0, py, uy, cy, ry, partial, hist_delta);
  // level 1: 256x256 -> ye1 (128x128)
  kx<2, 0><<<dim3(16, NIMG), 256, 0, stream>>>(
      bye0, bxe, px, ux, cx, rx, partial, hist_img, hist_delta);
  ky<2, 1><<<dim3(4, NIMG), 256, 0, stream>>>(
      bxe, bye1, py, uy, cy, ry, partial, hist_delta);
  // level 2: 128x128 -> ye2 (64x64), no uy
  kx<1, 0><<<dim3(8, NIMG), 256, 0, stream>>>(
      bye1, bxe, px, ux, cx, rx, partial, hist_img, hist_delta);
  ky<1, 0><<<dim3(1, NIMG), 256, 0, stream>>>(
      bxe, bye2, py, uy, cy, ry, partial, hist_delta);
  // levels 3-4 in LDS (stats only)
  klift_tail64<<<NIMG, 256, 0, stream>>>(bye2, px, ux, cx, rx, py, cy, ry,
                                         partial, hist_delta);
  kfinal<<<1, 256, 0, stream>>>(partial, hist_img, hist_delta, out);
}

// Round 16
// 89.165 us; speedup vs baseline: 2.0395x; 2.0395x over previous
//
#include <hip/hip_runtime.h>
#include <math.h>

#define NIMG 96
#define NSLOT 1024
#define RES_INV (1.0f / 262144.0f)   // 1 / (512*512)

// fmod(v+1,2)-1 for our range
__device__ __forceinline__ float wrap1(float v) {
  float t = v + 1.0f;
  return t - 2.0f * truncf(t * 0.5f) - 1.0f;
}
// bin for v in [-1,1): floor((v+1)*128) as single fma; clamp the 256 edge.
__device__ __forceinline__ int bin_fast(float v) {
  int b = (int)fmaf(v, 128.0f, 128.0f);
  return (b > 255) ? 255 : b;
}

// ---------------- Fused per-level kernel ------------------------------------
// x-lift in registers+shuffles (wave per row) -> LDS tile (XOR-swizzled for
// P=4); y-lift per thread-column in registers (window read once, 4 unrolled
// FMA-chain steps). Validity shrinks 1 pair-row/side/step; 4-pair-row halos
// keep the interior exact; outside-image rows are zeros = reference zero-pad.
// src: (NIMG, H, 2*W2); ye_out: (NIMG, H2, W2). W2 = H2 = 64*P.
template<int P, int SEGP, int USE_UY, int DO_IMG>
__global__ void __launch_bounds__(256) klift_fused(
    const float* __restrict__ src, float* __restrict__ ye_out,
    const float* __restrict__ kpx, const float* __restrict__ kux,
    const float* __restrict__ kcx, const float* __restrict__ krx,
    const float* __restrict__ kpy, const float* __restrict__ kuy,
    const float* __restrict__ kcy, const float* __restrict__ kry,
    double* __restrict__ partial,
    unsigned* __restrict__ hist_img, unsigned* __restrict__ hist_delta)
{
  constexpr int W2 = 64 * P;          // pairs per row = out width
  constexpr int H2 = W2;              // pair-rows in image (square levels)
  constexpr int H  = 2 * H2;          // input rows
  constexpr int NP = SEGP + 8;        // LDS pair-rows (4 halo each side)
  constexpr int NR = 2 * NP;          // LDS input rows
  constexpr int NITER = NR / 4;       // x-rows per wave
  __shared__ float tile[NR][W2];
  __shared__ unsigned shd[2][256];
  __shared__ unsigned shi[2][256];

  const int t = threadIdx.x, w = t >> 6, lane = t & 63;
  const int hsel = w >> 1;
  const int img = blockIdx.y;
  const int R0 = blockIdx.x * SEGP;        // first interior pair-row
  const int base_in = 2 * R0 - 8;          // input row of LDS row 0

  shd[0][t] = 0; shd[1][t] = 0;
  if (DO_IMG) { shi[0][t] = 0; shi[1][t] = 0; }
  __syncthreads();

  const float px0 = kpx[0], px1 = kpx[1], px2 = kpx[2];
  const float ux0 = kux[0], ux1 = kux[1], ux2 = kux[2];
  const float cx0 = kcx[0], cx1 = kcx[1], cx2 = kcx[2];
  const float rx0 = krx[0], rx1 = krx[1], rx2 = krx[2];
  const float py0 = kpy[0], py1 = kpy[1], py2 = kpy[2];
  const float uy0 = kuy[0], uy1 = kuy[1], uy2 = kuy[2];
  const float cy0 = kcy[0], cy1 = kcy[1], cy2 = kcy[2];
  const float ry0 = kry[0], ry1 = kry[1], ry2 = kry[2];

  const float* ip = src + (size_t)img * H * (2 * W2);
  float sqi = 0.f, sqd = 0.f;

  // signed-constant lifting step: d[j] = fma(k0,prev, fma(k1,s, fma(k2,nxt, d)))
  auto stepm = [&](float (&d)[P], float (&s)[P], float k0, float k1, float k2) {
    float L = __shfl_up(s[P - 1], 1); if (lane == 0) L = 0.f;
    float R = __shfl_down(s[0], 1);   if (lane == 63) R = 0.f;
    float prev = L;
#pragma unroll
    for (int j = 0; j < P; j++) {
      float nxt = (j == P - 1) ? R : s[(j + 1) < P ? (j + 1) : 0];
      d[j] = fmaf(k0, prev, fmaf(k1, s[j], fmaf(k2, nxt, d[j])));
      prev = s[j];
    }
  };
  auto ldrow = [&](int lr, float4& A, float4& B, bool chk) {
    const int gin = base_in + lr;
    if (!chk || ((unsigned)gin < (unsigned)H)) {
      const float* rp = ip + (size_t)gin * (2 * W2) + lane * (2 * P);
      if (P == 1) { float2 v = *(const float2*)rp; A.x = v.x; A.y = v.y; }
      else {
        A = *(const float4*)rp;
        if (P == 4) B = *(const float4*)(rp + 4);
      }
    } else {
      A = make_float4(0.f, 0.f, 0.f, 0.f);
      B = make_float4(0.f, 0.f, 0.f, 0.f);
    }
  };

  // swizzled write column (P=4 only): 16B chunk c -> c ^ ((c>>3)&7)
  const int wcol = (P == 4) ? ((lane ^ ((lane >> 3) & 7)) * 4)
                 : (P == 2) ? (lane * 2) : lane;

  // ---- x phase: wave w handles LDS rows w, w+4, ...; fully unrolled ----
  float4 cA = make_float4(0.f,0.f,0.f,0.f), cB = cA, nA = cA, nB = cA;
  ldrow(w, cA, cB, true);
#pragma unroll
  for (int i = 0; i < NITER; ++i) {
    const int lr = w + 4 * i;
    if (i + 1 < NITER)
      ldrow(lr + 4, nA, nB, (i + 1 < 2) || (i + 1 >= NITER - 2));
    const bool owned = (i >= 2) && (i < NITER - 2);   // compile-time
    float e[P], o[P];
    e[0] = cA.x; o[0] = cA.y;
    if (P >= 2) { e[P > 1 ? 1 : 0] = cA.z; o[P > 1 ? 1 : 0] = cA.w; }
    if (P == 4) {
      e[P > 2 ? 2 : 0] = cB.x; o[P > 2 ? 2 : 0] = cB.y;
      e[P > 3 ? 3 : 0] = cB.z; o[P > 3 ? 3 : 0] = cB.w;
    }
    if (DO_IMG && owned) {
#pragma unroll
      for (int j = 0; j < P; j++) {
        sqi += e[j] * e[j] + o[j] * o[j];
        atomicAdd(&shi[hsel][bin_fast(e[j])], 1u);
        atomicAdd(&shi[hsel][bin_fast(o[j])], 1u);
      }
    }
    stepm(o, e, -px0, -px1, -px2);
    stepm(e, o,  ux0,  ux1,  ux2);
    stepm(o, e, -cx0, -cx1, -cx2);
    stepm(e, o,  rx0,  rx1,  rx2);
    if (P == 4) {
      *(float4*)&tile[lr][wcol] =
          make_float4(e[0], e[P > 1 ? 1 : 0], e[P > 2 ? 2 : 0], e[P > 3 ? 3 : 0]);
    } else if (P == 2) {
      *(float2*)&tile[lr][wcol] = make_float2(e[0], e[P > 1 ? 1 : 0]);
    } else {
      tile[lr][wcol] = e[0];
    }
    if (owned) {
#pragma unroll
      for (int j = 0; j < P; j++) {
        float d = wrap1(o[j]);
        sqd += d * d;
        atomicAdd(&shd[hsel][bin_fast(d)], 1u);
      }
    }
    cA = nA; cB = nB;
  }
  __syncthreads();

  // ---- y phase: register-column lifting ------------------------------------
  {
    constexpr int NSP = 256 / W2;            // column splits
    constexpr int LEN = SEGP / NSP;          // interior pair-rows per thread
    constexpr int WIN = LEN + 8;             // window pair-rows per thread
    const int col = t % W2;
    const int half = t / W2;
    const int q0 = half * LEN;               // local window start (pair-rows)
    int colr;
    if (P == 4) {
      const int ch = (col >> 2) ^ ((col >> 5) & 7);
      colr = (ch << 2) | (col & 3);
    } else colr = col;

    float ee[WIN], oo[WIN];
#pragma unroll
    for (int q = 0; q < WIN; ++q) {
      ee[q] = tile[2 * (q0 + q)][colr];
      oo[q] = tile[2 * (q0 + q) + 1][colr];
    }
#pragma unroll
    for (int q = 0; q < WIN; ++q) {
      float U = (q > 0) ? ee[q - 1] : 0.f;
      float D = (q < WIN - 1) ? ee[q + 1] : 0.f;
      oo[q] = fmaf(-py0, U, fmaf(-py1, ee[q], fmaf(-py2, D, oo[q])));
    }
    if (USE_UY) {
#pragma unroll
      for (int q = 0; q < WIN; ++q) {
        float U = (q > 0) ? oo[q - 1] : 0.f;
        float D = (q < WIN - 1) ? oo[q + 1] : 0.f;
        ee[q] = fmaf(uy0, U, fmaf(uy1, oo[q], fmaf(uy2, D, ee[q])));
      }
    }
#pragma unroll
    for (int q = 0; q < WIN; ++q) {
      float U = (q > 0) ? ee[q - 1] : 0.f;
      float D = (q < WIN - 1) ? ee[q + 1] : 0.f;
      oo[q] = fmaf(-cy0, U, fmaf(-cy1, ee[q], fmaf(-cy2, D, oo[q])));
    }
#pragma unroll
    for (int q = 0; q < WIN; ++q) {
      float U = (q > 0) ? oo[q - 1] : 0.f;
      float D = (q < WIN - 1) ? oo[q + 1] : 0.f;
      ee[q] = fmaf(ry0, U, fmaf(ry1, oo[q], fmaf(ry2, D, ee[q])));
    }
    float* outp = ye_out + (size_t)img * H2 * W2 + col;
#pragma unroll
    for (int q = 4; q < 4 + LEN; ++q) {
      const int g = R0 + q0 + q - 4;
      float d = wrap1(oo[q]);
      sqd += d * d;
      atomicAdd(&shd[hsel][bin_fast(d)], 1u);
      outp[(size_t)g * W2] = ee[q];
    }
  }

  // ---- reduce + flush ----
  for (int off = 32; off; off >>= 1) {
    sqd += __shfl_down(sqd, off);
    if (DO_IMG) sqi += __shfl_down(sqi, off);
  }
  if (lane == 0) {
    const int bid = blockIdx.x + blockIdx.y * gridDim.x;
    const int slot = (bid * 4 + w) & (NSLOT - 1);
    atomicAdd(&partial[NSLOT + slot], (double)sqd);
    if (DO_IMG) atomicAdd(&partial[slot], (double)sqi);
  }
  __syncthreads();
  unsigned hd = shd[0][t] + shd[1][t];
  if (hd) atomicAdd(&hist_delta[img * 256 + t], hd);
  if (DO_IMG) {
    unsigned hi = shi[0][t] + shi[1][t];
    if (hi) atomicAdd(&hist_img[img * 256 + t], hi);
  }
}

// ---------------- Tail: levels 3-4 on 64x64 in LDS, 1 block = 1 image -------
// uy is NOT applied at lvl>=2, so py and cy steps merge: yo -= conv(ye, py+cy).
__global__ void __launch_bounds__(256) klift_tail64(
    const float* __restrict__ src,
    const float* __restrict__ kpx, const float* __restrict__ kux,
    const float* __restrict__ kcx, const float* __restrict__ krx,
    const float* __restrict__ kpy, const float* __restrict__ kcy,
    const float* __restrict__ kry,
    double* __restrict__ partial, unsigned* __restrict__ hist_delta)
{
  __shared__ float tile[64][65];
  __shared__ unsigned shd[256];
  const int t = threadIdx.x;
  const int img = blockIdx.x;
  shd[t] = 0;

  const float* sp = src + (size_t)img * 64 * 64;
  for (int idx = t; idx < 64 * 16; idx += 256) {
    const int r = idx >> 4, c4 = (idx & 15) << 2;
    float4 v = *(const float4*)(sp + r * 64 + c4);
    tile[r][c4] = v.x; tile[r][c4 + 1] = v.y;
    tile[r][c4 + 2] = v.z; tile[r][c4 + 3] = v.w;
  }
  const float px0 = kpx[0], px1 = kpx[1], px2 = kpx[2];
  const float ux0 = kux[0], ux1 = kux[1], ux2 = kux[2];
  const float cx0 = kcx[0], cx1 = kcx[1], cx2 = kcx[2];
  const float rx0 = krx[0], rx1 = krx[1], rx2 = krx[2];
  const float pc0 = kpy[0] + kcy[0], pc1 = kpy[1] + kcy[1], pc2 = kpy[2] + kcy[2];
  const float ry0 = kry[0], ry1 = kry[1], ry2 = kry[2];
  float sqd = 0.f;
  __syncthreads();

  for (int l = 0; l < 2; ++l) {
    const int s = 1 << l, n = 64 >> l, half = n >> 1;
    const int totx = n * half;

    for (int idx = t; idx < totx; idx += 256) {
      const int r = (idx / half) * s, c = idx % half;
      float L = (c > 0) ? tile[r][(2 * c - 2) * s] : 0.f;
      float M = tile[r][2 * c * s];
      float R = (c < half - 1) ? tile[r][(2 * c + 2) * s] : 0.f;
      tile[r][(2 * c + 1) * s] -= px0 * L + px1 * M + px2 * R;
    }
    __syncthreads();
    for (int idx = t; idx < totx; idx += 256) {
      const int r = (idx / half) * s, c = idx % half;
      float L = (c > 0) ? tile[r][(2 * c - 1) * s] : 0.f;
      float M = tile[r][(2 * c + 1) * s];
      float R = (c < half - 1) ? tile[r][(2 * c + 3) * s] : 0.f;
      tile[r][2 * c * s] += ux0 * L + ux1 * M + ux2 * R;
    }
    __syncthreads();
    for (int idx = t; idx < totx; idx += 256) {
      const int r = (idx / half) * s, c = idx % half;
      float L = (c > 0) ? tile[r][(2 * c - 2) * s] : 0.f;
      float M = tile[r][2 * c * s];
      float R = (c < half - 1) ? tile[r][(2 * c + 2) * s] : 0.f;
      tile[r][(2 * c + 1) * s] -= cx0 * L + cx1 * M + cx2 * R;
    }
    __syncthreads();
    for (int idx = t; idx < totx; idx += 256) {
      const int r = (idx / half) * s, c = idx % half;
      float L = (c > 0) ? tile[r][(2 * c - 1) * s] : 0.f;
      float M = tile[r][(2 * c + 1) * s];
      float R = (c < half - 1) ? tile[r][(2 * c + 3) * s] : 0.f;
      tile[r][2 * c * s] += rx0 * L + rx1 * M + rx2 * R;
    }
    __syncthreads();
    for (int idx = t; idx < totx; idx += 256) {
      const int r = (idx / half) * s, c = idx % half;
      float d = wrap1(tile[r][(2 * c + 1) * s]);
      sqd += d * d;
      atomicAdd(&shd[bin_fast(d)], 1u);
    }
    const int toty = half * half;
    for (int idx = t; idx < toty; idx += 256) {
      const int r = idx / half, j = idx % half, col = j * 2 * s;
      float U = (r > 0) ? tile[(2 * r - 2) * s][col] : 0.f;
      float M = tile[(2 * r) * s][col];
      float D = (r < half - 1) ? tile[(2 * r + 2) * s][col] : 0.f;
      tile[(2 * r + 1) * s][col] -= pc0 * U + pc1 * M + pc2 * D;
    }
    __syncthreads();
    for (int idx = t; idx < toty; idx += 256) {
      const int r = idx / half, j = idx % half, col = j * 2 * s;
      float U = (r > 0) ? tile[(2 * r - 1) * s][col] : 0.f;
      float M = tile[(2 * r + 1) * s][col];
      float D = (r < half - 1) ? tile[(2 * r + 3) * s][col] : 0.f;
      tile[(2 * r) * s][col] += ry0 * U + ry1 * M + ry2 * D;
    }
    __syncthreads();
    for (int idx = t; idx < toty; idx += 256) {
      const int r = idx / half, j = idx % half, col = j * 2 * s;
      float d = wrap1(tile[(2 * r + 1) * s][col]);
      sqd += d * d;
      atomicAdd(&shd[bin_fast(d)], 1u);
      if (l == 1) {
        float d2 = wrap1(tile[(2 * r) * s][col]);
        sqd += d2 * d2;
        atomicAdd(&shd[bin_fast(d2)], 1u);
      }
    }
    __syncthreads();
  }

  for (int off = 32; off; off >>= 1) sqd += __shfl_down(sqd, off);
  __shared__ float swv[4];
  if ((t & 63) == 0) swv[t >> 6] = sqd;
  __syncthreads();
  if (t == 0) {
    double tot = (double)swv[0] + swv[1] + swv[2] + swv[3];
    atomicAdd(&partial[NSLOT + (img & (NSLOT - 1))], tot);
  }
  unsigned hd = shd[t];
  if (hd) atomicAdd(&hist_delta[img * 256 + t], hd);
}

// ---------------- Final reduction: entropies + losses -----------------------
__global__ void __launch_bounds__(256) kfinal(
    const double* __restrict__ partial,
    const unsigned* __restrict__ hist_img,
    const unsigned* __restrict__ hist_delta,
    float* __restrict__ out)
{
  __shared__ double sI[256], sD[256], sPi[256], sPd[256];
  const int t = threadIdx.x;
  double entI = 0.0, entD = 0.0;
  for (int img = 0; img < NIMG; ++img) {
    unsigned ci = hist_img[img * 256 + t];
    if (ci) { float p = (float)ci * RES_INV; entI += (double)(-p * log2f(p)); }
    unsigned cd = hist_delta[img * 256 + t];
    if (cd) { float p = (float)cd * RES_INV; entD += (double)(-p * log2f(p)); }
  }
  double pi = 0.0, pd = 0.0;
  for (int s = t; s < NSLOT; s += 256) {
    pi += partial[s];
    pd += partial[NSLOT + s];
  }
  sI[t] = entI; sD[t] = entD; sPi[t] = pi; sPd[t] = pd;
  __syncthreads();
  for (int s = 128; s; s >>= 1) {
    if (t < s) {
      sI[t] += sI[t + s]; sD[t] += sD[t + s];
      sPi[t] += sPi[t + s]; sPd[t] += sPd[t + s];
    }
    __syncthreads();
  }
  if (t == 0) {
    const double tot = (double)NIMG * 262144.0;
    out[0] = (float)(255.0 * sqrt(sPd[0] / tot));  // loss1 (deltas)
    out[1] = (float)(255.0 * sqrt(sPi[0] / tot));  // loss0 (img)
    out[2] = (float)(sI[0] / (8.0 * NIMG));        // invCR0
    out[3] = (float)(sD[0] / (8.0 * NIMG));        // invCR1
  }
}

extern "C" void kernel_launch(void* const* d_in, const int* in_sizes, int n_in,
                              void* d_out, int out_size, void* d_ws, size_t ws_size,
                              hipStream_t stream)
{
  const float* x  = (const float*)d_in[0];
  const float* px = (const float*)d_in[1];
  const float* ux = (const float*)d_in[2];
  const float* cx = (const float*)d_in[3];
  const float* rx = (const float*)d_in[4];
  const float* py = (const float*)d_in[5];
  const float* uy = (const float*)d_in[6];
  const float* cy = (const float*)d_in[7];
  const float* ry = (const float*)d_in[8];
  float* out = (float*)d_out;

  char* ws = (char*)d_ws;
  double*   partial    = (double*)ws;
  unsigned* hist_img   = (unsigned*)(ws + 2 * NSLOT * 8);
  unsigned* hist_delta = (unsigned*)(ws + 2 * NSLOT * 8 + NIMG * 256 * 4);
  float* buf0 = (float*)(ws + (1 << 20));                        // ye0: 25.2MB
  float* buf1 = (float*)(ws + (1 << 20) + ((size_t)32 << 20));   // ye1: 6.3MB
  float* buf2 = (float*)(ws + (1 << 20) + ((size_t)40 << 20));   // ye2: 1.6MB

  hipMemsetAsync(ws, 0, 2 * NSLOT * 8 + 2 * NIMG * 256 * 4, stream);

  // level 0: 512x512 -> ye0 (256x256), img+delta stats. 32 stripes of 8 pair-rows.
  klift_fused<4, 8, 1, 1><<<dim3(32, NIMG), 256, 0, stream>>>(
      x, buf0, px, ux, cx, rx, py, uy, cy, ry, partial, hist_img, hist_delta);
  // level 1: 256x256 -> ye1 (128x128). 16 stripes.
  klift_fused<2, 8, 1, 0><<<dim3(16, NIMG), 256, 0, stream>>>(
      buf0, buf1, px, ux, cx, rx, py, uy, cy, ry, partial, hist_img, hist_delta);
  // level 2: 128x128 -> ye2 (64x64), no uy. 8 stripes.
  klift_fused<1, 8, 0, 0><<<dim3(8, NIMG), 256, 0, stream>>>(
      buf1, buf2, px, ux, cx, rx, py, uy, cy, ry, partial, hist_img, hist_delta);
  // levels 3-4 in LDS (stats only)
  klift_tail64<<<NIMG, 256, 0, stream>>>(buf2, px, ux, cx, rx, py, cy, ry,
                                         partial, hist_delta);
  kfinal<<<1, 256, 0, stream>>>(partial, hist_img, hist_delta, out);
}